// Round 14
// baseline (3960.235 us; speedup 1.0000x reference)
//
#include <hip/hip_runtime.h>
#include <hip/hip_fp16.h>

// LSTM forecaster: B=256, T=512, D_IN=64, H=1024, out = h_final @ Wout + bout.
// Round 14 = R13 with the h-EXCHANGE moved from MALL-bypass reads to CACHED reads
// + rotation-based coherence. Theory: R10-R13 + R12's confounded experiment show
// the step is bound by 32 MB/step of L2-bypass h reads (64x read amplification
// at the coherence point, ~4.5 TB/s service). Fix:
//  (1) h loads = plain cached loads; R4-proven m=xcd>>1 mapping puts ONE m-slice
//      per XCD -> first toucher misses to MALL (~128KB/XCD/step), 31 other WGs
//      hit L2 -> MALL read volume drops 32 MB -> ~1 MB/step.
//  (2) Coherence WITHOUT per-step invalidates: 8 ROTATING h buffers (slot=t&7);
//      a slot's L2/L1 lines are re-touched only 8 steps later, and ONE
//      fence(acquire, agent) every 8 steps (incl. t=0, which also covers
//      graph-replay staleness) invalidates L1+L2 in every window. W/bias live in
//      registers; h/x lines are single-use -> the inv discards only dead data.
//  (3) Producer publish / flags / poll byte-identical to R13 (wave-0 packed
//      bypass-atomic stores + vmcnt drain + agent-scope flag; m-group poll wave).
// R4 failed with cached reads because it fenced 256x/step AFTER loads were in
// flight (thrash); here it's 32 redundant invs per XCD per 8 steps, before loads.

#define T_STEPS 512
#define HID 1024
#define GRID 256
#define NTHR 512
#define NSLOT 8

typedef __attribute__((ext_vector_type(8))) _Float16 half8;
typedef __attribute__((ext_vector_type(4))) float f32x4;
typedef __attribute__((ext_vector_type(2))) float f32x2;

__device__ __forceinline__ float sigm(float v) {
    return __builtin_amdgcn_rcpf(1.0f + __expf(-v));
}
__device__ __forceinline__ float tanh_fast(float v) {
    return 2.0f * __builtin_amdgcn_rcpf(1.0f + __expf(-2.0f * v)) - 1.0f;
}

// Pack W [1088][4096] f32 -> Wp fp16 [n(64)][kb(136)][col(64)][kin(8)]
// col c of group n maps to original column (c&3)*1024 + n*16 + (c>>2)  (gate-interleaved).
__global__ void pack_w(const float* __restrict__ W, _Float16* __restrict__ Wp) {
    int idx = blockIdx.x * 256 + threadIdx.x;
    const int total = 64 * 136 * 64;
    if (idx >= total) return;
    int col = idx & 63;
    int kb = (idx >> 6) % 136;
    int n = (idx >> 6) / 136;
    int oc = ((col & 3) << 10) + (n << 4) + (col >> 2);
    const float* src = W + (size_t)(kb * 8) * 4096 + oc;
    _Float16* dst = Wp + (size_t)idx * 8;
#pragma unroll
    for (int j = 0; j < 8; j++) dst[j] = (_Float16)src[(size_t)j * 4096];
}

__global__ void __launch_bounds__(NTHR, 2) lstm_persist(
    const float* __restrict__ x,      // [256][512][64] f32
    const _Float16* __restrict__ Wp,  // packed W fp16
    const float* __restrict__ bias,   // [4096] f32
    _Float16* __restrict__ hbuf,      // [8][128][256][8] fp16  (slot, kb, b, kin)
    float* __restrict__ hfinal,       // [256][1024] f32
    unsigned int* bar)                // [256] arrival words (id=(m<<6)+n), 64B apart
{
    __shared__ float P[4 * 64 * 64];  // 64 KiB (proven size)
    _Float16* hstage = (_Float16*)P;  // 2 KiB overlay on plane 0 ([64][16])

    int wg = blockIdx.x;
    // XCD-pair mapping (R4-proven): m = xcd>>1 -> each XCD hosts exactly one
    // m-group slice -> cached h reads are 32-way L2-shared per XCD.
    int xcd = wg & 7;
    int m = xcd >> 1;                       // 0..3
    int n = ((xcd & 1) << 5) + (wg >> 3);   // 0..63
    int B0 = m << 6;
    int barId = (m << 6) + n;

    int tid = threadIdx.x;
    int wave = tid >> 6;   // 0..7
    int lane = tid & 63;
    int l15 = lane & 15, l4 = lane >> 4;
    int bb = tid & 63;
    int u0 = tid >> 6;     // activation: units 2*u0, 2*u0+1

    // per-thread bias: q -> (b=bb, u=2*u0+q), gates i,f,g,o
    float breg[2][4];
#pragma unroll
    for (int q = 0; q < 2; q++) {
        int u = (u0 << 1) + q;
#pragma unroll
        for (int g = 0; g < 4; g++) breg[q][g] = bias[(g << 10) + (n << 4) + u];
    }

    float cst[2] = {0.f, 0.f};

    const size_t HB = (size_t)128 * 256 * 8;  // elements per slot (512 KB)
    const _Float16* WpBase = Wp + (size_t)n * 136 * 64 * 8;

    // ---- W prologue: wave w owns h-chunks {2+w, 10+w, 18+w, 26+w} (covers 2..33),
    //      fragments register-resident for all 512 steps ----
    half8 wfr[4][4];
#pragma unroll
    for (int j = 0; j < 4; j++) {
        int kb = ((2 + wave + 8 * j) << 2) + l4;  // 8..135
        const _Float16* wp = WpBase + ((size_t)kb << 9);
#pragma unroll
        for (int nn = 0; nn < 4; nn++) wfr[j][nn] = *(const half8*)(wp + (((nn << 4) + l15) << 3));
    }

    // ---- Wx prologue: waves 2,3 keep their x-chunk W fragments resident ----
    half8 bxr[4];
    if (wave == 2 || wave == 3) {
        int kb = ((wave - 2) << 2) + l4;  // 0..7
        const _Float16* wp = WpBase + ((size_t)kb << 9);
#pragma unroll
        for (int nn = 0; nn < 4; nn++) bxr[nn] = *(const half8*)(wp + (((nn << 4) + l15) << 3));
    }

    f32x4 acc[4][4];
#pragma unroll
    for (int i = 0; i < 4; i++)
#pragma unroll
        for (int j = 0; j < 4; j++) acc[i][j] = (f32x4){0.f, 0.f, 0.f, 0.f};

    // x(tt) @ Wx into acc — waves 2,3 only; W from registers, x cached loads
    auto XPREP = [&](int tt) {
        if (wave == 2 || wave == 3) {
            int kb = ((wave - 2) << 2) + l4;  // 0..7
#pragma unroll
            for (int mm = 0; mm < 4; mm++) {
                const float* xp = x + ((size_t)(B0 + (mm << 4) + l15) * T_STEPS + tt) * 64 + (kb << 3);
                f32x4 lo = *(const f32x4*)xp;
                f32x4 hi = *(const f32x4*)(xp + 4);
                half8 v;
                v[0] = (_Float16)lo[0]; v[1] = (_Float16)lo[1];
                v[2] = (_Float16)lo[2]; v[3] = (_Float16)lo[3];
                v[4] = (_Float16)hi[0]; v[5] = (_Float16)hi[1];
                v[6] = (_Float16)hi[2]; v[7] = (_Float16)hi[3];
#pragma unroll
                for (int nn = 0; nn < 4; nn++)
                    acc[mm][nn] = __builtin_amdgcn_mfma_f32_16x16x32_f16(v, bxr[nn], acc[mm][nn], 0, 0, 0);
            }
        }
    };

    XPREP(0);

    for (int t = 0; t < T_STEPS; t++) {
        // ---- every 8 steps: L1+L2 acquire-invalidate BEFORE any h load.
        //      Guarantees no slot line survives between consecutive touches
        //      (8 steps apart); t=0 instance also kills cross-replay staleness.
        if ((t & 7) == 0) {
            __builtin_amdgcn_fence(__ATOMIC_ACQUIRE, "agent");
        }

        const _Float16* cur = hbuf + (size_t)((t + NSLOT - 1) & (NSLOT - 1)) * HB;  // h(t-1)
        _Float16* nxt = hbuf + (size_t)(t & (NSLOT - 1)) * HB;                      // h(t)

        // ---- h @ Wh: plain CACHED 16B loads (L2-shared within XCD), register W ----
#pragma unroll
        for (int j = 0; j < 4; j++) {
            int kb = ((2 + wave + 8 * j) << 2) + l4;  // 8..135
            const _Float16* hp = cur + (((size_t)(kb - 8) << 8) + B0 + l15) * 8;
            half8 ah[4];
#pragma unroll
            for (int mm = 0; mm < 4; mm++) ah[mm] = *(const half8*)(hp + (mm << 7));
#pragma unroll
            for (int mm = 0; mm < 4; mm++)
#pragma unroll
                for (int nn = 0; nn < 4; nn++)
                    acc[mm][nn] = __builtin_amdgcn_mfma_f32_16x16x32_f16(ah[mm], wfr[j][nn],
                                                                         acc[mm][nn], 0, 0, 0);
        }

        // ---- two-pass cross-wave reduction, 4 planes of 16KB, XOR-swizzled ----
        if (wave < 4) {
#pragma unroll
            for (int mm = 0; mm < 4; mm++)
#pragma unroll
                for (int nn = 0; nn < 4; nn++) {
                    int c = (nn << 4) + l15;
                    int bblk = (mm << 2) + l4;
                    int word = (((wave << 6) + c) << 6) + (((bblk ^ l15) & 15) << 2);
                    *(f32x4*)&P[word] = acc[mm][nn];
                }
        }
        __syncthreads();
        if (wave >= 4) {
            int pw = wave - 4;
#pragma unroll
            for (int mm = 0; mm < 4; mm++)
#pragma unroll
                for (int nn = 0; nn < 4; nn++) {
                    int c = (nn << 4) + l15;
                    int bblk = (mm << 2) + l4;
                    int word = (((pw << 6) + c) << 6) + (((bblk ^ l15) & 15) << 2);
                    f32x4 v = *(f32x4*)&P[word];
                    v += acc[mm][nn];
                    *(f32x4*)&P[word] = v;
                }
        }
        __syncthreads();

        // ---- activations: thread handles (b=bb, u=2*u0+q), q=0,1 ----
        union { _Float16 h2[2]; unsigned int u; } hs;
        float hvf[2];
#pragma unroll
        for (int q = 0; q < 2; q++) {
            int u = (u0 << 1) + q;
            float g4[4];
#pragma unroll
            for (int g = 0; g < 4; g++) {
                int c = (u << 2) + g;
                int word = (c << 6) + (((((bb >> 2) ^ c) & 15) << 2) | (bb & 3));
                float s = breg[q][g];
#pragma unroll
                for (int w = 0; w < 4; w++) s += P[(w << 12) + word];
                g4[g] = s;
            }
            float ig = sigm(g4[0]);
            float fg = sigm(g4[1]);
            float gg = tanh_fast(g4[2]);
            float og = sigm(g4[3]);
            float cv = fg * cst[q] + ig * gg;
            cst[q] = cv;
            float hv = og * tanh_fast(cv);
            hs.h2[q] = (_Float16)hv;
            hvf[q] = hv;
        }
        if (t == T_STEPS - 1) {
            int ug0 = (n << 4) + (u0 << 1);
            f32x2 hv2; hv2[0] = hvf[0]; hv2[1] = hvf[1];
            *(f32x2*)&hfinal[(size_t)(B0 + bb) * HID + ug0] = hv2;
            break;  // uniform; no h publish after last step
        }

        // ---- pack h into overlay tile ----
        __syncthreads();  // S_act: ALL P reads complete before overlay writes
        *(unsigned int*)&hstage[(bb << 4) + (u0 << 1)] = hs.u;
        __syncthreads();  // S_pack: overlay tile complete

        // ---- wave 0 ALONE: publish 128x16B bypass-atomic, drain, flag (R13-proven) ----
        if (wave == 0) {
#pragma unroll
            for (int it = 0; it < 2; it++) {
                int item = lane + (it << 6);         // 0..127
                int row = item >> 1, hf = item & 1;  // batch row, 8-unit half
                union { half8 h; unsigned long long u[2]; } v;
                v.h = *(const half8*)&hstage[(row << 4) + (hf << 3)];
                // dst: hbuf[slot t][kb'=2n+hf][B0+row][0..7] (16B, 8B-aligned)
                unsigned long long* dst =
                    (unsigned long long*)(nxt + (((size_t)((n << 1) + hf) << 8) + B0 + row) * 8);
                __hip_atomic_store(dst, v.u[0], __ATOMIC_RELAXED, __HIP_MEMORY_SCOPE_AGENT);
                __hip_atomic_store(dst + 1, v.u[1], __ATOMIC_RELAXED, __HIP_MEMORY_SCOPE_AGENT);
            }
            asm volatile("s_waitcnt vmcnt(0)" ::: "memory");  // wave-0 stores ack'd at MALL
            if (lane == 0)
                __hip_atomic_store(bar + ((size_t)barId << 4), (unsigned int)(t + 1),
                                   __ATOMIC_RELAXED, __HIP_MEMORY_SCOPE_AGENT);
        }

        // ---- all waves: reset acc; waves 2,3 fold x(t+1); poll wave waits ----
#pragma unroll
        for (int i = 0; i < 4; i++)
#pragma unroll
            for (int j = 0; j < 4; j++) acc[i][j] = (f32x4){0.f, 0.f, 0.f, 0.f};
        XPREP(t + 1);
        // m-group-local barrier: one wave polls the group's 64 arrival words
        if (tid >= 256 && tid < 320) {
            const unsigned int* ap = bar + (((m << 6) + (tid - 256)) << 4);
            while (__hip_atomic_load(ap, __ATOMIC_RELAXED, __HIP_MEMORY_SCOPE_AGENT) <
                   (unsigned int)(t + 1)) {
                __builtin_amdgcn_s_sleep(1);
            }
        }
        __syncthreads();
    }
}

// out[b][j] = bout[j] + sum_k hfinal[b][k] * Wout[k][j]   (256 blocks x 64 threads)
__global__ void proj_kernel(const float* __restrict__ hfinal, const float* __restrict__ Wout,
                            const float* __restrict__ bout, float* __restrict__ out) {
    int b = blockIdx.x;
    int l = threadIdx.x;
    float acc[24];
#pragma unroll
    for (int j = 0; j < 24; j++) acc[j] = 0.f;
    for (int i = 0; i < 16; i++) {
        int k = i * 64 + l;
        float h = hfinal[(size_t)b * HID + k];
        const float* wr = Wout + (size_t)k * 24;
#pragma unroll
        for (int j = 0; j < 24; j++) acc[j] += h * wr[j];
    }
    __shared__ float red[24][65];
#pragma unroll
    for (int j = 0; j < 24; j++) red[j][l] = acc[j];
    __syncthreads();
    if (l < 24) {
        float s = bout[l];
#pragma unroll
        for (int i = 0; i < 64; i++) s += red[l][i];
        out[b * 24 + l] = s;
    }
}

extern "C" void kernel_launch(void* const* d_in, const int* in_sizes, int n_in,
                              void* d_out, int out_size, void* d_ws, size_t ws_size,
                              hipStream_t stream) {
    const float* x = (const float*)d_in[0];     // [256][512][64]
    const float* W = (const float*)d_in[1];     // [1088][4096]
    const float* b = (const float*)d_in[2];     // [4096]
    const float* Wout = (const float*)d_in[3];  // [1024][24]
    const float* bout = (const float*)d_in[4];  // [24]
    float* out = (float*)d_out;

    char* ws = (char*)d_ws;
    _Float16* Wp = (_Float16*)ws;                                 // 8,912,896 B
    _Float16* hbuf = (_Float16*)(ws + 8912896);                   // 4,194,304 B (8 slots)
    float* hfinal = (float*)(ws + 8912896 + 4194304);             // 1,048,576 B
    unsigned int* bar = (unsigned int*)(ws + 8912896 + 5242880);  // 16,384 B

    // zero h slot 7 (h(-1) = 0, read at t=0) and barrier words, every call
    hipMemsetAsync((char*)hbuf + 7 * 524288, 0, 524288, stream);
    hipMemsetAsync(bar, 0, 16384, stream);

    pack_w<<<(64 * 136 * 64 + 255) / 256, 256, 0, stream>>>(W, Wp);

    void* args[6];
    args[0] = (void*)&x;
    args[1] = (void*)&Wp;
    args[2] = (void*)&b;
    args[3] = (void*)&hbuf;
    args[4] = (void*)&hfinal;
    args[5] = (void*)&bar;
    hipLaunchCooperativeKernel((void*)lstm_persist, dim3(GRID), dim3(NTHR), args, 0, stream);

    proj_kernel<<<256, 64, 0, stream>>>(hfinal, Wout, bout, out);
}

// Round 15
// 3613.165 us; speedup vs baseline: 1.0961x; 1.0961x over previous
//
#include <hip/hip_runtime.h>
#include <hip/hip_fp16.h>

// LSTM forecaster: B=256, T=512, D_IN=64, H=1024, out = h_final @ Wout + bout.
// Round 15: TWO-CHAIN PHASE PIPELINE. R12/R14 proved the step is a fixed serial
// LATENCY chain (~3 MALL RTs + compute), invariant under traffic changes. LSTM
// batch rows are independent recurrences -> split each WG's 64 rows into chains
// A (rows B0..B0+32) and B (B0+32..B0+64), interleaved: (t,A),(t,B),(t+1,A)...
//  - Poll for the NEXT phase's chain runs at the END of the current phase,
//    overlapping the publish drain; its flags were set one full phase earlier
//    -> near-instant detection; each chain's exchange latency gets a whole
//    opposite-chain phase to complete off the critical path.
//  - Per phase: half compute (acc[2][4], 32 rows), same total MFMA/step.
//  - Per-chain 2-slot double buffer = per-chain instance of the PROVEN R13
//    protocol (same overwrite-safety induction). No rotation, no fences (R14
//    reverted). All sync primitives byte-identical to R13: agent-atomic u64
//    h loads/stores, wave-0 packed publish + vmcnt drain + agent flag,
//    m-group poll wave, monotonic values.

#define T_STEPS 512
#define HID 1024
#define GRID 256
#define NTHR 512

typedef __attribute__((ext_vector_type(8))) _Float16 half8;
typedef __attribute__((ext_vector_type(4))) float f32x4;
typedef unsigned long long u64;

__device__ __forceinline__ float sigm(float v) {
    return __builtin_amdgcn_rcpf(1.0f + __expf(-v));
}
__device__ __forceinline__ float tanh_fast(float v) {
    return 2.0f * __builtin_amdgcn_rcpf(1.0f + __expf(-2.0f * v)) - 1.0f;
}

// Pack W [1088][4096] f32 -> Wp fp16 [n(64)][kb(136)][col(64)][kin(8)]
// col c of group n maps to original column (c&3)*1024 + n*16 + (c>>2)  (gate-interleaved).
__global__ void pack_w(const float* __restrict__ W, _Float16* __restrict__ Wp) {
    int idx = blockIdx.x * 256 + threadIdx.x;
    const int total = 64 * 136 * 64;
    if (idx >= total) return;
    int col = idx & 63;
    int kb = (idx >> 6) % 136;
    int n = (idx >> 6) / 136;
    int oc = ((col & 3) << 10) + (n << 4) + (col >> 2);
    const float* src = W + (size_t)(kb * 8) * 4096 + oc;
    _Float16* dst = Wp + (size_t)idx * 8;
#pragma unroll
    for (int j = 0; j < 8; j++) dst[j] = (_Float16)src[(size_t)j * 4096];
}

__global__ void __launch_bounds__(NTHR, 2) lstm_persist(
    const float* __restrict__ x,      // [256][512][64] f32
    const _Float16* __restrict__ Wp,  // packed W fp16
    const float* __restrict__ bias,   // [4096] f32
    _Float16* __restrict__ hbuf,      // [2][128][256][8] fp16  (slot, kb, b, kin)
    float* __restrict__ hfinal,       // [256][1024] f32
    unsigned int* bar)                // [2][256] flag words (chain, wg), 64B apart
{
    __shared__ float P[4 * 64 * 32];  // 32 KiB: 4 planes [col(64)][row(32)], swizzled
    _Float16* hstage = (_Float16*)P;  // 1 KiB overlay on plane 0 ([32 rows][16 units])

    int wg = blockIdx.x;
    // XCD-aware mapping (R13-proven): XCD x gets n in [8x,8x+8) for all 4 m.
    int xcd = wg & 7, slot = wg >> 3;
    int n = (xcd << 3) + (slot & 7);  // 0..63
    int m = slot >> 3;                 // 0..3  (m-group = flag words [64m,64m+64))
    int B0 = m << 6;

    int tid = threadIdx.x;
    int wave = tid >> 6;   // 0..7
    int lane = tid & 63;
    int l15 = lane & 15, l4 = lane >> 4;
    int r_ = tid & 31;     // activation: batch row within chain tile
    int u_ = tid >> 5;     // activation: unit 0..15

    // per-thread bias for unit u_ (gates i,f,g,o) — shared by both chains
    float breg_[4];
#pragma unroll
    for (int g = 0; g < 4; g++) breg_[g] = bias[(g << 10) + (n << 4) + u_];

    float cstA = 0.f, cstB = 0.f;  // cell state: one (row,unit) per chain

    const size_t HB = (size_t)128 * 256 * 8;
    const _Float16* WpBase = Wp + (size_t)n * 136 * 64 * 8;

    // ---- W prologue: wave w owns h-chunks {2+w, 10+w, 18+w, 26+w} (covers 2..33) ----
    half8 wfr[4][4];
#pragma unroll
    for (int j = 0; j < 4; j++) {
        int kb = ((2 + wave + 8 * j) << 2) + l4;  // 8..135
        const _Float16* wp = WpBase + ((size_t)kb << 9);
#pragma unroll
        for (int nn = 0; nn < 4; nn++) wfr[j][nn] = *(const half8*)(wp + (((nn << 4) + l15) << 3));
    }
    // ---- Wx prologue: waves 2,3 keep x-chunk W fragments resident ----
    half8 bxr[4];
    if (wave == 2 || wave == 3) {
        int kb = ((wave - 2) << 2) + l4;  // 0..7
        const _Float16* wp = WpBase + ((size_t)kb << 9);
#pragma unroll
        for (int nn = 0; nn < 4; nn++) bxr[nn] = *(const half8*)(wp + (((nn << 4) + l15) << 3));
    }

    // ================= one phase: chain c (rows B0+32c..+32) at step t =================
    // publish iff t < 511; end-poll for NEXT phase: chain pollC, target pollT (<0 skip).
    auto PHASE = [&](int c, float& cst, int t, int pollC, int pollT) {
        const _Float16* cur = hbuf + (size_t)(t & 1) * HB;        // h(t-1)
        _Float16* nxt = hbuf + (size_t)((t + 1) & 1) * HB;        // h(t)
        int B0c = B0 + (c << 5);

        f32x4 acc[2][4];
#pragma unroll
        for (int i = 0; i < 2; i++)
#pragma unroll
            for (int j = 0; j < 4; j++) acc[i][j] = (f32x4){0.f, 0.f, 0.f, 0.f};

        // x part: waves 2,3 (chunks 0,1), W from registers
        if (wave == 2 || wave == 3) {
            int kb = ((wave - 2) << 2) + l4;  // 0..7
#pragma unroll
            for (int mm = 0; mm < 2; mm++) {
                const float* xp = x + ((size_t)(B0c + (mm << 4) + l15) * T_STEPS + t) * 64 + (kb << 3);
                f32x4 lo = *(const f32x4*)xp;
                f32x4 hi = *(const f32x4*)(xp + 4);
                half8 v;
                v[0] = (_Float16)lo[0]; v[1] = (_Float16)lo[1];
                v[2] = (_Float16)lo[2]; v[3] = (_Float16)lo[3];
                v[4] = (_Float16)hi[0]; v[5] = (_Float16)hi[1];
                v[6] = (_Float16)hi[2]; v[7] = (_Float16)hi[3];
#pragma unroll
                for (int nn = 0; nn < 4; nn++)
                    acc[mm][nn] = __builtin_amdgcn_mfma_f32_16x16x32_f16(v, bxr[nn], acc[mm][nn], 0, 0, 0);
            }
        }

        // h part: coherent u64 agent-atomic loads (proven), register W
#pragma unroll
        for (int j = 0; j < 4; j++) {
            int kb = ((2 + wave + 8 * j) << 2) + l4;  // 8..135
            u64* hp = (u64*)(cur + (((size_t)(kb - 8) << 8) + B0c + l15) * 8);
            half8 ah[2];
#pragma unroll
            for (int mm = 0; mm < 2; mm++) {
                union { u64 u[2]; half8 h; } cv;
                cv.u[0] = __hip_atomic_load(hp + (mm << 5), __ATOMIC_RELAXED, __HIP_MEMORY_SCOPE_AGENT);
                cv.u[1] = __hip_atomic_load(hp + (mm << 5) + 1, __ATOMIC_RELAXED, __HIP_MEMORY_SCOPE_AGENT);
                ah[mm] = cv.h;
            }
#pragma unroll
            for (int mm = 0; mm < 2; mm++)
#pragma unroll
                for (int nn = 0; nn < 4; nn++)
                    acc[mm][nn] = __builtin_amdgcn_mfma_f32_16x16x32_f16(ah[mm], wfr[j][nn],
                                                                         acc[mm][nn], 0, 0, 0);
        }

        // two-pass reduction: 4 planes of [64 cols][32 rows], XOR-swizzled
        if (wave < 4) {
#pragma unroll
            for (int mm = 0; mm < 2; mm++)
#pragma unroll
                for (int nn = 0; nn < 4; nn++) {
                    int cc = (nn << 4) + l15;
                    int rblk = (mm << 2) + l4;
                    int word = (wave << 11) + (cc << 5) + (((rblk ^ (cc & 7)) & 7) << 2);
                    *(f32x4*)&P[word] = acc[mm][nn];
                }
        }
        __syncthreads();
        if (wave >= 4) {
#pragma unroll
            for (int mm = 0; mm < 2; mm++)
#pragma unroll
                for (int nn = 0; nn < 4; nn++) {
                    int cc = (nn << 4) + l15;
                    int rblk = (mm << 2) + l4;
                    int word = ((wave - 4) << 11) + (cc << 5) + (((rblk ^ (cc & 7)) & 7) << 2);
                    f32x4 v = *(f32x4*)&P[word];
                    v += acc[mm][nn];
                    *(f32x4*)&P[word] = v;
                }
        }
        __syncthreads();

        // activation: thread handles (row r_, unit u_)
        float g4[4];
#pragma unroll
        for (int g = 0; g < 4; g++) {
            int cc = (u_ << 2) + g;
            int word = (cc << 5) + ((((r_ >> 2) ^ (cc & 7)) & 7) << 2) + (r_ & 3);
            float s = breg_[g];
#pragma unroll
            for (int w = 0; w < 4; w++) s += P[(w << 11) + word];
            g4[g] = s;
        }
        float ig = sigm(g4[0]);
        float fg = sigm(g4[1]);
        float gg = tanh_fast(g4[2]);
        float og = sigm(g4[3]);
        float cv = fg * cst + ig * gg;
        cst = cv;
        float hv = og * tanh_fast(cv);

        if (t == T_STEPS - 1) {
            hfinal[(size_t)(B0c + r_) * HID + (n << 4) + u_] = hv;
        } else {
            __syncthreads();  // ALL P reads complete before overlay write
            hstage[(r_ << 4) + u_] = (_Float16)hv;
            __syncthreads();  // overlay tile complete
            // wave 0 ALONE: publish 64x16B, drain, flag (off other waves' path)
            if (wave == 0) {
                int row = lane >> 1, hf = lane & 1;  // row 0..31, 8-unit half
                union { half8 h; u64 u[2]; } v;
                v.h = *(const half8*)&hstage[(row << 4) + (hf << 3)];
                u64* dst = (u64*)(nxt + (((size_t)((n << 1) + hf) << 8) + B0c + row) * 8);
                __hip_atomic_store(dst, v.u[0], __ATOMIC_RELAXED, __HIP_MEMORY_SCOPE_AGENT);
                __hip_atomic_store(dst + 1, v.u[1], __ATOMIC_RELAXED, __HIP_MEMORY_SCOPE_AGENT);
                asm volatile("s_waitcnt vmcnt(0)" ::: "memory");  // ack'd at MALL
                if (lane == 0)
                    __hip_atomic_store(bar + (((c << 8) + wg) << 4), (unsigned int)(t + 1),
                                       __ATOMIC_RELAXED, __HIP_MEMORY_SCOPE_AGENT);
            }
        }

        // end-poll for the NEXT phase (overlaps wave 0's drain): m-group words
        if (pollT >= 0 && tid >= 256 && tid < 320) {
            const unsigned int* ap = bar + (((pollC << 8) + (m << 6) + (tid - 256)) << 4);
            while (__hip_atomic_load(ap, __ATOMIC_RELAXED, __HIP_MEMORY_SCOPE_AGENT) <
                   (unsigned int)pollT) {
                __builtin_amdgcn_s_sleep(1);
            }
        }
        __syncthreads();
    };

    // ---- phase sequence: (0,A),(0,B),(1,A),...,(511,A),(511,B) ----
    for (int t = 0; t < T_STEPS; t++) {
        // end of (t,A): next phase (t,B) needs flags_B >= t (set at end of (t-1,B))
        PHASE(0, cstA, t, 1, t);
        // end of (t,B): next phase (t+1,A) needs flags_A >= t+1 (set at end of (t,A));
        // no next phase after (511,B)
        PHASE(1, cstB, t, 0, (t < T_STEPS - 1) ? (t + 1) : -1);
    }
}

// out[b][j] = bout[j] + sum_k hfinal[b][k] * Wout[k][j]   (256 blocks x 64 threads)
__global__ void proj_kernel(const float* __restrict__ hfinal, const float* __restrict__ Wout,
                            const float* __restrict__ bout, float* __restrict__ out) {
    int b = blockIdx.x;
    int l = threadIdx.x;
    float acc[24];
#pragma unroll
    for (int j = 0; j < 24; j++) acc[j] = 0.f;
    for (int i = 0; i < 16; i++) {
        int k = i * 64 + l;
        float h = hfinal[(size_t)b * HID + k];
        const float* wr = Wout + (size_t)k * 24;
#pragma unroll
        for (int j = 0; j < 24; j++) acc[j] += h * wr[j];
    }
    __shared__ float red[24][65];
#pragma unroll
    for (int j = 0; j < 24; j++) red[j][l] = acc[j];
    __syncthreads();
    if (l < 24) {
        float s = bout[l];
#pragma unroll
        for (int i = 0; i < 64; i++) s += red[l][i];
        out[b * 24 + l] = s;
    }
}

extern "C" void kernel_launch(void* const* d_in, const int* in_sizes, int n_in,
                              void* d_out, int out_size, void* d_ws, size_t ws_size,
                              hipStream_t stream) {
    const float* x = (const float*)d_in[0];     // [256][512][64]
    const float* W = (const float*)d_in[1];     // [1088][4096]
    const float* b = (const float*)d_in[2];     // [4096]
    const float* Wout = (const float*)d_in[3];  // [1024][24]
    const float* bout = (const float*)d_in[4];  // [24]
    float* out = (float*)d_out;

    char* ws = (char*)d_ws;
    _Float16* Wp = (_Float16*)ws;                                  // 8,912,896 B
    _Float16* hbuf = (_Float16*)(ws + 8912896);                    // 1,048,576 B (2 slots)
    float* hfinal = (float*)(ws + 8912896 + 1048576);              // 1,048,576 B
    unsigned int* bar = (unsigned int*)(ws + 8912896 + 2097152);   // 32,768 B (2 chains)

    // zero h slot 0 (h(-1)=0 for both chains) and all flag words, every call
    hipMemsetAsync(hbuf, 0, 524288, stream);
    hipMemsetAsync(bar, 0, 32768, stream);

    pack_w<<<(64 * 136 * 64 + 255) / 256, 256, 0, stream>>>(W, Wp);

    void* args[6];
    args[0] = (void*)&x;
    args[1] = (void*)&Wp;
    args[2] = (void*)&b;
    args[3] = (void*)&hbuf;
    args[4] = (void*)&hfinal;
    args[5] = (void*)&bar;
    hipLaunchCooperativeKernel((void*)lstm_persist, dim3(GRID), dim3(NTHR), args, 0, stream);

    proj_kernel<<<256, 64, 0, stream>>>(hfinal, Wout, bout, out);
}